// Round 1
// baseline (1324.455 us; speedup 1.0000x reference)
//
#include <hip/hip_runtime.h>
#include <math.h>

#define TT 200
#define CHN 256
#define FEAT 2048
#define DUR 64
#define RESN 16

// ---------------- base conv1d (2048->256, k=3, pad=1) + relu ----------------
__global__ void base_conv_kernel(const float* __restrict__ x, const float* __restrict__ w,
                                 const float* __restrict__ bias, float* __restrict__ h) {
  int t = blockIdx.x * 64 + threadIdx.x;
  int o = blockIdx.y;
  int b = blockIdx.z;
  if (t >= TT) return;
  const float* xb = x + b * FEAT * TT;
  const float* wo = w + o * FEAT * 3;
  float acc = bias[o];
  #pragma unroll 4
  for (int c = 0; c < FEAT; ++c) {
    float xm = (t >= 1) ? xb[c*TT + t - 1] : 0.f;
    float x0 = xb[c*TT + t];
    float xp = (t + 1 < TT) ? xb[c*TT + t + 1] : 0.f;
    acc += wo[c*3+0]*xm + wo[c*3+1]*x0 + wo[c*3+2]*xp;
  }
  h[(b*CHN + o)*TT + t] = fmaxf(acc, 0.f);
}

// ---------------- generic 256x256 projection: out = [relu](W @ in) [+ resid] ----------------
__global__ void proj_kernel(const float* __restrict__ W, const float* __restrict__ in,
                            const float* __restrict__ resid, float* __restrict__ out,
                            int do_relu) {
  int t = blockIdx.x * 64 + threadIdx.x;
  int o = blockIdx.y;
  int b = blockIdx.z;
  if (t >= TT) return;
  const float* wrow = W + o * CHN;
  const float* inb = in + b * CHN * TT;
  float acc = 0.f;
  #pragma unroll 8
  for (int c = 0; c < CHN; ++c) acc += wrow[c] * inb[c*TT + t];
  if (do_relu) acc = fmaxf(acc, 0.f);
  if (resid) acc += resid[(b*CHN + o)*TT + t];
  out[(b*CHN + o)*TT + t] = acc;
}

// ---------------- banded attention: scores -> 2-mask softmax -> out, A_sum ----------------
__global__ void attn_kernel(const float* __restrict__ q, const float* __restrict__ k,
                            const float* __restrict__ v, const float* __restrict__ pos,
                            float* __restrict__ Aout, float* __restrict__ out) {
  int t = blockIdx.x;
  int b = blockIdx.y;
  int lane = threadIdx.x;  // 64
  const float* qb = q + b * CHN * TT;
  const float* kb = k + b * CHN * TT;
  const float* vb = v + b * CHN * TT;
  float qc[4];
  #pragma unroll
  for (int i = 0; i < 4; ++i) qc[i] = qb[(lane + 64*i)*TT + t];

  float sc[17];
  #pragma unroll
  for (int j = 0; j < 17; ++j) {
    int s = t - 8 + j;
    bool inr = (s >= 0) && (s < TT);
    int ss = s < 0 ? 0 : (s > TT-1 ? TT-1 : s);
    float p = 0.f;
    #pragma unroll
    for (int i = 0; i < 4; ++i) p += qc[i] * kb[(lane + 64*i)*TT + ss];
    #pragma unroll
    for (int off = 32; off > 0; off >>= 1) p += __shfl_xor(p, off, 64);
    sc[j] = inr ? (p * 0.0625f + pos[t*TT + ss]) : -3.0e38f;
  }
  // softmax over band8 (all 17) and band4 (j=4..12)
  float m8 = sc[0];
  #pragma unroll
  for (int j = 1; j < 17; ++j) m8 = fmaxf(m8, sc[j]);
  float m4 = sc[4];
  #pragma unroll
  for (int j = 5; j < 13; ++j) m4 = fmaxf(m4, sc[j]);
  float e8[17], s8 = 0.f;
  #pragma unroll
  for (int j = 0; j < 17; ++j) { e8[j] = expf(sc[j] - m8); s8 += e8[j]; }
  float e4[9], s4 = 0.f;
  #pragma unroll
  for (int j = 0; j < 9; ++j) { e4[j] = expf(sc[4+j] - m4); s4 += e4[j]; }
  float i8 = 1.f / s8, i4 = 1.f / s4;
  float asum[17];
  #pragma unroll
  for (int j = 0; j < 17; ++j) {
    float a = e8[j] * i8;
    if (j >= 4 && j <= 12) a += e4[j-4] * i4;
    asum[j] = a;
  }
  // out[c,t] = sum_s asum[s] * v[c,s]
  #pragma unroll
  for (int i = 0; i < 4; ++i) {
    float acc = 0.f;
    #pragma unroll
    for (int j = 0; j < 17; ++j) {
      int s = t - 8 + j;
      int ss = s < 0 ? 0 : (s > TT-1 ? TT-1 : s);
      acc += asum[j] * vb[(lane + 64*i)*TT + ss];
    }
    out[(b*CHN + lane + 64*i)*TT + t] = acc;
  }
  // dense A row (zeros outside band)
  __shared__ float lds_a[17];
  #pragma unroll
  for (int j = 0; j < 17; ++j) if (lane == j) lds_a[j] = asum[j];
  __syncthreads();
  for (int s = lane; s < TT; s += 64) {
    int j = s - (t - 8);
    float a = (j >= 0 && j < 17) ? lds_a[j] : 0.f;
    Aout[(b*TT + t)*TT + s] = a;
  }
}

// ---------------- start/end head: sigmoid(w . feat + b) ----------------
__global__ void head_kernel(const float* __restrict__ feat, const float* __restrict__ w,
                            const float* __restrict__ bias, float* __restrict__ outp) {
  int t = blockIdx.x * 64 + threadIdx.x;
  int b = blockIdx.y;
  if (t >= TT) return;
  float acc = bias[0];
  #pragma unroll 8
  for (int c = 0; c < CHN; ++c) acc += w[c] * feat[(b*CHN + c)*TT + t];
  outp[b*TT + t] = 1.f / (1.f + expf(-acc));
}

// ---------------- transpose cw1 into wT[r][c][o] ----------------
__global__ void w1t_kernel(const float* __restrict__ cw1, float* __restrict__ wT) {
  int idx = blockIdx.x * 256 + threadIdx.x;
  if (idx >= 128 * 4096) return;
  int o = idx >> 12;        // /4096
  int cr = idx & 4095;
  int c = cr >> 4;
  int r = cr & 15;
  wT[(r*CHN + c)*128 + o] = cw1[idx];
}

// ---------------- g[b][r][x][o] = sum_c wT[r][c][o] * cfeat[b][c][x] ----------------
__global__ void g_kernel(const float* __restrict__ wT, const float* __restrict__ cf,
                         float* __restrict__ g) {
  int o = threadIdx.x;      // 128
  int xt = blockIdx.x;      // 50 tiles of 4
  int r = blockIdx.y;       // 16
  int b = blockIdx.z;       // 2
  float acc[4] = {0.f, 0.f, 0.f, 0.f};
  const float* wp = wT + r*CHN*128 + o;
  const float* cp = cf + b*CHN*TT + xt*4;
  for (int c = 0; c < CHN; ++c) {
    float wv = wp[c*128];
    #pragma unroll
    for (int j = 0; j < 4; ++j) acc[j] += wv * cp[c*TT + j];
  }
  float* gp = g + ((b*RESN + r)*TT + xt*4)*128 + o;
  #pragma unroll
  for (int j = 0; j < 4; ++j) gp[j*128] = acc[j];
}

// ---------------- fused align + 1x1 conv (cw1) + relu -> y1[b][o][d][t] ----------------
__global__ void align_conv1_kernel(const float* __restrict__ g, const float* __restrict__ cb1,
                                   float* __restrict__ y1) {
  int o = threadIdx.x;      // 128
  int t = blockIdx.x;       // 200 (anchor start s)
  int d = blockIdx.y;       // 64  (duration)
  int b = blockIdx.z;
  bool vanch = (t + d) < TT;
  float clen = d + 1.0f;
  float xmin = vanch ? (t - clen * 0.5f) : 0.f;
  float xmax = vanch ? (t + d + clen * 0.5f) : 0.f;
  float acc = cb1[o];
  const float* gb = g + b*RESN*TT*128;
  #pragma unroll
  for (int r = 0; r < RESN; ++r) {
    float frac = (r + 0.5f) * (1.f/16.f);
    float p = xmin + (xmax - xmin) * frac;
    float x0 = floorf(p);
    float wf = p - x0;
    int x0i = (int)fminf(fmaxf(x0, 0.f), (float)(TT-1));
    int x1i = (int)fminf(fmaxf(x0 + 1.f, 0.f), (float)(TT-1));
    bool vp = (p >= -1.0f) && (p <= (float)TT);
    if (vp) {
      const float* gr = gb + r*TT*128;
      acc += (1.f - wf) * gr[x0i*128 + o] + wf * gr[x1i*128 + o];
    }
  }
  y1[((b*128 + o)*DUR + d)*TT + t] = fmaxf(acc, 0.f);
}

// ---------------- 3x3 conv 128->128, pad 1, relu; in/out [B][128][64][200] ----------------
__global__ void conv3x3_kernel(const float* __restrict__ in, const float* __restrict__ w,
                               const float* __restrict__ bias, float* __restrict__ out) {
  const int OT = 8;
  int t = blockIdx.x * 64 + threadIdx.x;
  int d = blockIdx.y;
  int zz = blockIdx.z;
  int b = zz >> 4;
  int og = zz & 15;
  if (t >= TT) return;
  float acc[OT];
  #pragma unroll
  for (int j = 0; j < OT; ++j) acc[j] = bias[og*OT + j];
  for (int i = 0; i < 128; ++i) {
    const float* ip = in + ((b*128 + i)*DUR)*TT;
    float vv[9];
    #pragma unroll
    for (int kd = 0; kd < 3; ++kd) {
      int dd = d + kd - 1;
      bool dok = (dd >= 0) && (dd < DUR);
      #pragma unroll
      for (int kt = 0; kt < 3; ++kt) {
        int tt2 = t + kt - 1;
        bool ok = dok && (tt2 >= 0) && (tt2 < TT);
        vv[kd*3 + kt] = ok ? ip[dd*TT + tt2] : 0.f;
      }
    }
    #pragma unroll
    for (int j = 0; j < OT; ++j) {
      const float* wp = w + ((og*OT + j)*128 + i)*9;
      #pragma unroll
      for (int kk = 0; kk < 9; ++kk) acc[j] += wp[kk] * vv[kk];
    }
  }
  #pragma unroll
  for (int j = 0; j < OT; ++j)
    out[((b*128 + og*OT + j)*DUR + d)*TT + t] = fmaxf(acc[j], 0.f);
}

// ---------------- final 1x1 conv 128->2 + sigmoid -> conf ----------------
__global__ void conv4_kernel(const float* __restrict__ in, const float* __restrict__ w,
                             const float* __restrict__ bias, float* __restrict__ conf) {
  int t = blockIdx.x * 64 + threadIdx.x;
  int d = blockIdx.y;
  int b = blockIdx.z;
  if (t >= TT) return;
  float a0 = bias[0], a1 = bias[1];
  #pragma unroll 4
  for (int i = 0; i < 128; ++i) {
    float vv = in[((b*128 + i)*DUR + d)*TT + t];
    a0 += w[i] * vv;
    a1 += w[128 + i] * vv;
  }
  conf[((b*2 + 0)*DUR + d)*TT + t] = 1.f / (1.f + expf(-a0));
  conf[((b*2 + 1)*DUR + d)*TT + t] = 1.f / (1.f + expf(-a1));
}

extern "C" void kernel_launch(void* const* d_in, const int* in_sizes, int n_in,
                              void* d_out, int out_size, void* d_ws, size_t ws_size,
                              hipStream_t stream) {
  const float* x       = (const float*)d_in[0];
  const float* base_w  = (const float*)d_in[1];
  const float* base_b  = (const float*)d_in[2];
  const float* wq      = (const float*)d_in[3];
  const float* wk      = (const float*)d_in[4];
  const float* wv      = (const float*)d_in[5];
  const float* wo      = (const float*)d_in[6];
  const float* pos     = (const float*)d_in[7];
  const float* start_w = (const float*)d_in[8];
  const float* start_b = (const float*)d_in[9];
  const float* end_w   = (const float*)d_in[10];
  const float* end_b   = (const float*)d_in[11];
  const float* cw1     = (const float*)d_in[12];
  const float* cb1     = (const float*)d_in[13];
  const float* cw2     = (const float*)d_in[14];
  const float* cb2     = (const float*)d_in[15];
  const float* cw3     = (const float*)d_in[16];
  const float* cb3     = (const float*)d_in[17];
  const float* cw4     = (const float*)d_in[18];
  const float* cb4     = (const float*)d_in[19];

  float* out = (float*)d_out;
  float* conf_out  = out;            // 2*2*64*200 = 51200
  float* start_out = out + 51200;    // 400
  float* end_out   = out + 51600;    // 400
  float* As_out    = out + 52000;    // 80000
  float* Ae_out    = out + 132000;   // 80000
  float* Ap_out    = out + 212000;   // 80000

  float* ws = (float*)d_ws;
  float* h        = ws;              // 102400
  float* basef    = ws + 102400;
  float* qb       = ws + 204800;
  float* kb       = ws + 307200;
  float* vb       = ws + 409600;
  float* attn_o   = ws + 512000;
  float* sfeat    = ws + 614400;
  float* efeat    = ws + 716800;
  float* cfeat    = ws + 819200;
  float* A_scr    = ws + 921600;     // 80000
  float* wT       = ws + 1001600;    // 524288
  float* gbuf     = ws + 1525888;    // 819200
  float* y1       = ws + 2345088;    // 3276800
  float* y2       = ws + 5621888;    // 3276800

  dim3 b64(64);

  // base conv
  base_conv_kernel<<<dim3(4, 256, 2), b64, 0, stream>>>(x, base_w, base_b, h);

  // 4 rslots: (input, output, A destination)
  const float* rs_in[4]  = { h, basef, basef, basef };
  float*       rs_out[4] = { basef, sfeat, efeat, cfeat };
  float*       rs_A[4]   = { A_scr, As_out, Ae_out, Ap_out };
  for (int i = 0; i < 4; ++i) {
    const float* Wq = wq + i*65536;
    const float* Wk = wk + i*65536;
    const float* Wv = wv + i*65536;
    const float* Wo = wo + i*65536;
    proj_kernel<<<dim3(4, 256, 2), b64, 0, stream>>>(Wq, rs_in[i], nullptr, qb, 0);
    proj_kernel<<<dim3(4, 256, 2), b64, 0, stream>>>(Wk, rs_in[i], nullptr, kb, 0);
    proj_kernel<<<dim3(4, 256, 2), b64, 0, stream>>>(Wv, rs_in[i], nullptr, vb, 0);
    attn_kernel<<<dim3(200, 2), b64, 0, stream>>>(qb, kb, vb, pos, rs_A[i], attn_o);
    proj_kernel<<<dim3(4, 256, 2), b64, 0, stream>>>(Wo, attn_o, rs_in[i], rs_out[i], 1);
  }

  // heads
  head_kernel<<<dim3(4, 2), b64, 0, stream>>>(sfeat, start_w, start_b, start_out);
  head_kernel<<<dim3(4, 2), b64, 0, stream>>>(efeat, end_w, end_b, end_out);

  // proposal branch: wT, g, fused align+1x1, 3x3 convs, final 1x1
  w1t_kernel<<<dim3(2048), dim3(256), 0, stream>>>(cw1, wT);
  g_kernel<<<dim3(50, 16, 2), dim3(128), 0, stream>>>(wT, cfeat, gbuf);
  align_conv1_kernel<<<dim3(200, 64, 2), dim3(128), 0, stream>>>(gbuf, cb1, y1);
  conv3x3_kernel<<<dim3(4, 64, 32), b64, 0, stream>>>(y1, cw2, cb2, y2);
  conv3x3_kernel<<<dim3(4, 64, 32), b64, 0, stream>>>(y2, cw3, cb3, y1);
  conv4_kernel<<<dim3(4, 64, 2), b64, 0, stream>>>(y1, cw4, cb4, conf_out);
}

// Round 2
// 1086.104 us; speedup vs baseline: 1.2195x; 1.2195x over previous
//
#include <hip/hip_runtime.h>
#include <math.h>

#define TT 200
#define CHN 256
#define FEAT 2048
#define DUR 64
#define RESN 16

// ---------------- base conv1d (2048->256, k=3, pad=1) + relu ----------------
__global__ void base_conv_kernel(const float* __restrict__ x, const float* __restrict__ w,
                                 const float* __restrict__ bias, float* __restrict__ h) {
  int t = blockIdx.x * 64 + threadIdx.x;
  int o = blockIdx.y;
  int b = blockIdx.z;
  if (t >= TT) return;
  const float* xb = x + b * FEAT * TT;
  const float* wo = w + o * FEAT * 3;
  float acc = bias[o];
  #pragma unroll 4
  for (int c = 0; c < FEAT; ++c) {
    float xm = (t >= 1) ? xb[c*TT + t - 1] : 0.f;
    float x0 = xb[c*TT + t];
    float xp = (t + 1 < TT) ? xb[c*TT + t + 1] : 0.f;
    acc += wo[c*3+0]*xm + wo[c*3+1]*x0 + wo[c*3+2]*xp;
  }
  h[(b*CHN + o)*TT + t] = fmaxf(acc, 0.f);
}

// ---------------- fused q/k/v projection ----------------
__global__ void qkv_kernel(const float* __restrict__ Wq, const float* __restrict__ Wk,
                           const float* __restrict__ Wv, const float* __restrict__ in,
                           float* __restrict__ q, float* __restrict__ k, float* __restrict__ v) {
  int t = blockIdx.x * 64 + threadIdx.x;
  int o = blockIdx.y;
  int b = blockIdx.z;
  if (t >= TT) return;
  const float* inb = in + b * CHN * TT;
  const float* wqr = Wq + o * CHN;
  const float* wkr = Wk + o * CHN;
  const float* wvr = Wv + o * CHN;
  float aq = 0.f, ak = 0.f, av = 0.f;
  #pragma unroll 8
  for (int c = 0; c < CHN; ++c) {
    float xv = inb[c*TT + t];
    aq += wqr[c] * xv;
    ak += wkr[c] * xv;
    av += wvr[c] * xv;
  }
  q[(b*CHN + o)*TT + t] = aq;
  k[(b*CHN + o)*TT + t] = ak;
  v[(b*CHN + o)*TT + t] = av;
}

// ---------------- output projection: out = relu(W @ in) + resid ----------------
__global__ void proj_kernel(const float* __restrict__ W, const float* __restrict__ in,
                            const float* __restrict__ resid, float* __restrict__ out,
                            int do_relu) {
  int t = blockIdx.x * 64 + threadIdx.x;
  int o = blockIdx.y;
  int b = blockIdx.z;
  if (t >= TT) return;
  const float* wrow = W + o * CHN;
  const float* inb = in + b * CHN * TT;
  float acc = 0.f;
  #pragma unroll 8
  for (int c = 0; c < CHN; ++c) acc += wrow[c] * inb[c*TT + t];
  if (do_relu) acc = fmaxf(acc, 0.f);
  if (resid) acc += resid[(b*CHN + o)*TT + t];
  out[(b*CHN + o)*TT + t] = acc;
}

// ---------------- banded attention: scores -> 2-mask softmax -> out, A_sum ----------------
__global__ void attn_kernel(const float* __restrict__ q, const float* __restrict__ k,
                            const float* __restrict__ v, const float* __restrict__ pos,
                            float* __restrict__ Aout, float* __restrict__ out) {
  int t = blockIdx.x;
  int b = blockIdx.y;
  int lane = threadIdx.x;  // 64
  const float* qb = q + b * CHN * TT;
  const float* kb = k + b * CHN * TT;
  const float* vb = v + b * CHN * TT;
  float qc[4];
  #pragma unroll
  for (int i = 0; i < 4; ++i) qc[i] = qb[(lane + 64*i)*TT + t];

  float sc[17];
  #pragma unroll
  for (int j = 0; j < 17; ++j) {
    int s = t - 8 + j;
    bool inr = (s >= 0) && (s < TT);
    int ss = s < 0 ? 0 : (s > TT-1 ? TT-1 : s);
    float p = 0.f;
    #pragma unroll
    for (int i = 0; i < 4; ++i) p += qc[i] * kb[(lane + 64*i)*TT + ss];
    #pragma unroll
    for (int off = 32; off > 0; off >>= 1) p += __shfl_xor(p, off, 64);
    sc[j] = inr ? (p * 0.0625f + pos[t*TT + ss]) : -3.0e38f;
  }
  float m8 = sc[0];
  #pragma unroll
  for (int j = 1; j < 17; ++j) m8 = fmaxf(m8, sc[j]);
  float m4 = sc[4];
  #pragma unroll
  for (int j = 5; j < 13; ++j) m4 = fmaxf(m4, sc[j]);
  float e8[17], s8 = 0.f;
  #pragma unroll
  for (int j = 0; j < 17; ++j) { e8[j] = expf(sc[j] - m8); s8 += e8[j]; }
  float e4[9], s4 = 0.f;
  #pragma unroll
  for (int j = 0; j < 9; ++j) { e4[j] = expf(sc[4+j] - m4); s4 += e4[j]; }
  float i8 = 1.f / s8, i4 = 1.f / s4;
  float asum[17];
  #pragma unroll
  for (int j = 0; j < 17; ++j) {
    float a = e8[j] * i8;
    if (j >= 4 && j <= 12) a += e4[j-4] * i4;
    asum[j] = a;
  }
  #pragma unroll
  for (int i = 0; i < 4; ++i) {
    float acc = 0.f;
    #pragma unroll
    for (int j = 0; j < 17; ++j) {
      int s = t - 8 + j;
      int ss = s < 0 ? 0 : (s > TT-1 ? TT-1 : s);
      acc += asum[j] * vb[(lane + 64*i)*TT + ss];
    }
    out[(b*CHN + lane + 64*i)*TT + t] = acc;
  }
  __shared__ float lds_a[17];
  #pragma unroll
  for (int j = 0; j < 17; ++j) if (lane == j) lds_a[j] = asum[j];
  __syncthreads();
  for (int s = lane; s < TT; s += 64) {
    int j = s - (t - 8);
    float a = (j >= 0 && j < 17) ? lds_a[j] : 0.f;
    Aout[(b*TT + t)*TT + s] = a;
  }
}

// ---------------- start/end head: sigmoid(w . feat + b) ----------------
__global__ void head_kernel(const float* __restrict__ feat, const float* __restrict__ w,
                            const float* __restrict__ bias, float* __restrict__ outp) {
  int t = blockIdx.x * 64 + threadIdx.x;
  int b = blockIdx.y;
  if (t >= TT) return;
  float acc = bias[0];
  #pragma unroll 8
  for (int c = 0; c < CHN; ++c) acc += w[c] * feat[(b*CHN + c)*TT + t];
  outp[b*TT + t] = 1.f / (1.f + expf(-acc));
}

// ---------------- transpose cw1 into wT[r][c][o] ----------------
__global__ void w1t_kernel(const float* __restrict__ cw1, float* __restrict__ wT) {
  int idx = blockIdx.x * 256 + threadIdx.x;
  if (idx >= 128 * 4096) return;
  int o = idx >> 12;
  int cr = idx & 4095;
  int c = cr >> 4;
  int r = cr & 15;
  wT[(r*CHN + c)*128 + o] = cw1[idx];
}

// ---------------- g[b][r][x][o] = sum_c wT[r][c][o] * cfeat[b][c][x] ----------------
__global__ void g_kernel(const float* __restrict__ wT, const float* __restrict__ cf,
                         float* __restrict__ g) {
  int o = threadIdx.x;      // 128
  int xt = blockIdx.x;      // 50 tiles of 4
  int r = blockIdx.y;       // 16
  int b = blockIdx.z;       // 2
  float acc[4] = {0.f, 0.f, 0.f, 0.f};
  const float* wp = wT + r*CHN*128 + o;
  const float* cp = cf + b*CHN*TT + xt*4;
  for (int c = 0; c < CHN; ++c) {
    float wv = wp[c*128];
    #pragma unroll
    for (int j = 0; j < 4; ++j) acc[j] += wv * cp[c*TT + j];
  }
  float* gp = g + ((b*RESN + r)*TT + xt*4)*128 + o;
  #pragma unroll
  for (int j = 0; j < 4; ++j) gp[j*128] = acc[j];
}

// ---------------- fused align + 1x1 conv (cw1) + relu -> y1[b][o][d][t] ----------------
__global__ void align_conv1_kernel(const float* __restrict__ g, const float* __restrict__ cb1,
                                   float* __restrict__ y1) {
  int o = threadIdx.x;      // 128
  int t = blockIdx.x;       // 200
  int d = blockIdx.y;       // 64
  int b = blockIdx.z;
  bool vanch = (t + d) < TT;
  float clen = d + 1.0f;
  float xmin = vanch ? (t - clen * 0.5f) : 0.f;
  float xmax = vanch ? (t + d + clen * 0.5f) : 0.f;
  float acc = cb1[o];
  const float* gb = g + b*RESN*TT*128;
  #pragma unroll
  for (int r = 0; r < RESN; ++r) {
    float frac = (r + 0.5f) * (1.f/16.f);
    float p = xmin + (xmax - xmin) * frac;
    float x0 = floorf(p);
    float wf = p - x0;
    int x0i = (int)fminf(fmaxf(x0, 0.f), (float)(TT-1));
    int x1i = (int)fminf(fmaxf(x0 + 1.f, 0.f), (float)(TT-1));
    bool vp = (p >= -1.0f) && (p <= (float)TT);
    if (vp) {
      const float* gr = gb + r*TT*128;
      acc += (1.f - wf) * gr[x0i*128 + o] + wf * gr[x1i*128 + o];
    }
  }
  y1[((b*128 + o)*DUR + d)*TT + t] = fmaxf(acc, 0.f);
}

// ---------------- LDS-tiled 3x3 conv 128->128, pad 1, relu ----------------
// Block: 256 threads = 4 waves. Output tile: 16 oc x 4 d x 64 t.
// Grid: (4 t-tiles, 16 d-tiles, b*8 + ocg) = 1024 blocks.
#define C3_CT 64
#define C3_CD 4
#define C3_COC 16
#define C3_CIC 8
__global__ __launch_bounds__(256, 4)
void conv3x3_kernel(const float* __restrict__ in, const float* __restrict__ w,
                    const float* __restrict__ bias, float* __restrict__ out) {
  __shared__ float tile[C3_CIC*6*68];   // [ic][row 6][col 68]
  __shared__ float wl[C3_COC*C3_CIC*12]; // [oc_local][ic][12], tail zeros
  int tid = threadIdx.x;
  int tl = tid & 63;
  int wg = tid >> 6;            // 0..3
  int t0 = blockIdx.x * C3_CT;
  int d0 = blockIdx.y * C3_CD;
  int z = blockIdx.z;
  int b = z >> 3;
  int ocg = z & 7;
  int t = t0 + tl;

  float acc[C3_CD][4];
  #pragma unroll
  for (int dd = 0; dd < C3_CD; ++dd)
    #pragma unroll
    for (int j = 0; j < 4; ++j) acc[dd][j] = 0.f;

  const float* inb = in + (size_t)b*128*DUR*TT;

  for (int ic0 = 0; ic0 < 128; ic0 += C3_CIC) {
    __syncthreads();
    // stage input tile: rows d0-1..d0+4, cols t0-1..t0+64 (66 valid of 68)
    for (int idx = tid; idx < C3_CIC*6*68; idx += 256) {
      int ic = idx / 408;
      int rem = idx - ic*408;
      int row = rem / 68;
      int col = rem - row*68;
      int gd = d0 + row - 1;
      int gt = t0 + col - 1;
      float vval = 0.f;
      if (col < 66 && (unsigned)gd < (unsigned)DUR && (unsigned)gt < (unsigned)TT)
        vval = inb[(ic0+ic)*DUR*TT + gd*TT + gt];
      tile[idx] = vval;
    }
    // stage weights
    for (int idx = tid; idx < C3_COC*C3_CIC*12; idx += 256) {
      int oc = idx / (C3_CIC*12);
      int rem = idx - oc*C3_CIC*12;
      int ic = rem / 12;
      int kk = rem - ic*12;
      float vval = 0.f;
      if (kk < 9)
        vval = w[((ocg*C3_COC+oc)*128 + ic0+ic)*9 + kk];
      wl[idx] = vval;
    }
    __syncthreads();
    for (int ic = 0; ic < C3_CIC; ++ic) {
      float vv[6][3];
      #pragma unroll
      for (int r = 0; r < 6; ++r)
        #pragma unroll
        for (int c2 = 0; c2 < 3; ++c2)
          vv[r][c2] = tile[ic*408 + r*68 + tl + c2];
      #pragma unroll
      for (int j = 0; j < 4; ++j) {
        int oc_l = wg*4 + j;   // wave-uniform -> LDS broadcast reads
        const float4* wp = (const float4*)(wl + (oc_l*C3_CIC + ic)*12);
        float4 w0 = wp[0], w1 = wp[1], w2 = wp[2];
        #pragma unroll
        for (int dd = 0; dd < C3_CD; ++dd) {
          float s = acc[dd][j];
          s += w0.x*vv[dd][0]   + w0.y*vv[dd][1]   + w0.z*vv[dd][2];
          s += w0.w*vv[dd+1][0] + w1.x*vv[dd+1][1] + w1.y*vv[dd+1][2];
          s += w1.z*vv[dd+2][0] + w1.w*vv[dd+2][1] + w2.x*vv[dd+2][2];
          acc[dd][j] = s;
        }
      }
    }
  }
  if (t < TT) {
    #pragma unroll
    for (int j = 0; j < 4; ++j) {
      int oc = ocg*C3_COC + wg*4 + j;
      float bv = bias[oc];
      #pragma unroll
      for (int dd = 0; dd < C3_CD; ++dd)
        out[((b*128+oc)*DUR + d0+dd)*TT + t] = fmaxf(acc[dd][j] + bv, 0.f);
    }
  }
}

// ---------------- final 1x1 conv 128->2 + sigmoid -> conf ----------------
__global__ void conv4_kernel(const float* __restrict__ in, const float* __restrict__ w,
                             const float* __restrict__ bias, float* __restrict__ conf) {
  int t = blockIdx.x * 64 + threadIdx.x;
  int d = blockIdx.y;
  int b = blockIdx.z;
  if (t >= TT) return;
  float a0 = bias[0], a1 = bias[1];
  #pragma unroll 4
  for (int i = 0; i < 128; ++i) {
    float vv = in[((b*128 + i)*DUR + d)*TT + t];
    a0 += w[i] * vv;
    a1 += w[128 + i] * vv;
  }
  conf[((b*2 + 0)*DUR + d)*TT + t] = 1.f / (1.f + expf(-a0));
  conf[((b*2 + 1)*DUR + d)*TT + t] = 1.f / (1.f + expf(-a1));
}

extern "C" void kernel_launch(void* const* d_in, const int* in_sizes, int n_in,
                              void* d_out, int out_size, void* d_ws, size_t ws_size,
                              hipStream_t stream) {
  const float* x       = (const float*)d_in[0];
  const float* base_w  = (const float*)d_in[1];
  const float* base_b  = (const float*)d_in[2];
  const float* wq      = (const float*)d_in[3];
  const float* wk      = (const float*)d_in[4];
  const float* wv      = (const float*)d_in[5];
  const float* wo      = (const float*)d_in[6];
  const float* pos     = (const float*)d_in[7];
  const float* start_w = (const float*)d_in[8];
  const float* start_b = (const float*)d_in[9];
  const float* end_w   = (const float*)d_in[10];
  const float* end_b   = (const float*)d_in[11];
  const float* cw1     = (const float*)d_in[12];
  const float* cb1     = (const float*)d_in[13];
  const float* cw2     = (const float*)d_in[14];
  const float* cb2     = (const float*)d_in[15];
  const float* cw3     = (const float*)d_in[16];
  const float* cb3     = (const float*)d_in[17];
  const float* cw4     = (const float*)d_in[18];
  const float* cb4     = (const float*)d_in[19];

  float* out = (float*)d_out;
  float* conf_out  = out;            // 51200
  float* start_out = out + 51200;    // 400
  float* end_out   = out + 51600;    // 400
  float* As_out    = out + 52000;    // 80000
  float* Ae_out    = out + 132000;   // 80000
  float* Ap_out    = out + 212000;   // 80000

  float* ws = (float*)d_ws;
  float* h        = ws;
  float* basef    = ws + 102400;
  float* qb       = ws + 204800;
  float* kb       = ws + 307200;
  float* vb       = ws + 409600;
  float* attn_o   = ws + 512000;
  float* sfeat    = ws + 614400;
  float* efeat    = ws + 716800;
  float* cfeat    = ws + 819200;
  float* A_scr    = ws + 921600;
  float* wT       = ws + 1001600;
  float* gbuf     = ws + 1525888;
  float* y1       = ws + 2345088;
  float* y2       = ws + 5621888;

  dim3 b64(64);

  base_conv_kernel<<<dim3(4, 256, 2), b64, 0, stream>>>(x, base_w, base_b, h);

  const float* rs_in[4]  = { h, basef, basef, basef };
  float*       rs_out[4] = { basef, sfeat, efeat, cfeat };
  float*       rs_A[4]   = { A_scr, As_out, Ae_out, Ap_out };
  for (int i = 0; i < 4; ++i) {
    const float* Wq = wq + i*65536;
    const float* Wk = wk + i*65536;
    const float* Wv = wv + i*65536;
    const float* Wo = wo + i*65536;
    qkv_kernel<<<dim3(4, 256, 2), b64, 0, stream>>>(Wq, Wk, Wv, rs_in[i], qb, kb, vb);
    attn_kernel<<<dim3(200, 2), b64, 0, stream>>>(qb, kb, vb, pos, rs_A[i], attn_o);
    proj_kernel<<<dim3(4, 256, 2), b64, 0, stream>>>(Wo, attn_o, rs_in[i], rs_out[i], 1);
  }

  head_kernel<<<dim3(4, 2), b64, 0, stream>>>(sfeat, start_w, start_b, start_out);
  head_kernel<<<dim3(4, 2), b64, 0, stream>>>(efeat, end_w, end_b, end_out);

  w1t_kernel<<<dim3(2048), dim3(256), 0, stream>>>(cw1, wT);
  g_kernel<<<dim3(50, 16, 2), dim3(128), 0, stream>>>(wT, cfeat, gbuf);
  align_conv1_kernel<<<dim3(200, 64, 2), dim3(128), 0, stream>>>(gbuf, cb1, y1);
  conv3x3_kernel<<<dim3(4, 16, 16), dim3(256), 0, stream>>>(y1, cw2, cb2, y2);
  conv3x3_kernel<<<dim3(4, 16, 16), dim3(256), 0, stream>>>(y2, cw3, cb3, y1);
  conv4_kernel<<<dim3(4, 64, 2), b64, 0, stream>>>(y1, cw4, cb4, conf_out);
}

// Round 3
// 878.714 us; speedup vs baseline: 1.5073x; 1.2360x over previous
//
#include <hip/hip_runtime.h>
#include <math.h>

#define TT 200
#define CHN 256
#define FEAT 2048
#define DUR 64
#define RESN 16

// ---------------- base conv1d partial: 16oc x 64t tile over 256-c slice ----------------
// grid (4 t-tiles, 16 ocg, cs*2+b with cs<8), block 256 = 4 waves
__global__ __launch_bounds__(256, 4)
void base_conv_part(const float* __restrict__ x, const float* __restrict__ w,
                    float* __restrict__ partial) {
  __shared__ float xt[16*68];      // [ic][col], col 0..65 valid = t0-1 .. t0+64
  __shared__ float wl[16*16*4];    // [oc][ic][4] (k in 0..2, [3] pad)
  int tid = threadIdx.x;
  int tl = tid & 63, wg = tid >> 6;
  int t0 = blockIdx.x * 64;
  int ocg = blockIdx.y;
  int cs = blockIdx.z >> 1, b = blockIdx.z & 1;
  const float* xb = x + (size_t)b * FEAT * TT;
  float acc[4] = {0.f, 0.f, 0.f, 0.f};

  for (int ch = 0; ch < 16; ++ch) {
    int c0 = cs * 256 + ch * 16;
    __syncthreads();
    for (int idx = tid; idx < 16*68; idx += 256) {
      int ic = idx / 68, col = idx - ic*68;
      int gt = t0 + col - 1;
      float v = 0.f;
      if (col < 66 && (unsigned)gt < (unsigned)TT) v = xb[(c0+ic)*TT + gt];
      xt[idx] = v;
    }
    for (int idx = tid; idx < 16*16*3; idx += 256) {
      int oc = idx / 48, rem = idx - oc*48;
      int ic = rem / 3, kk = rem - ic*3;
      wl[(oc*16 + ic)*4 + kk] = w[((ocg*16+oc)*FEAT + c0+ic)*3 + kk];
    }
    __syncthreads();
    #pragma unroll
    for (int ic = 0; ic < 16; ++ic) {
      float v0 = xt[ic*68 + tl];
      float v1 = xt[ic*68 + tl + 1];
      float v2 = xt[ic*68 + tl + 2];
      #pragma unroll
      for (int j = 0; j < 4; ++j) {
        const float4 wv = *(const float4*)(wl + ((wg*4+j)*16 + ic)*4);
        acc[j] += wv.x*v0 + wv.y*v1 + wv.z*v2;
      }
    }
  }
  int t = t0 + tl;
  if (t < TT) {
    #pragma unroll
    for (int j = 0; j < 4; ++j) {
      int oc = ocg*16 + wg*4 + j;
      partial[((cs*2 + b)*CHN + oc)*TT + t] = acc[j];
    }
  }
}

__global__ void base_reduce(const float* __restrict__ partial, const float* __restrict__ bias,
                            float* __restrict__ h) {
  int idx = blockIdx.x * 256 + threadIdx.x;
  if (idx >= 2*CHN*TT) return;
  int b = idx / (CHN*TT);
  int rem = idx - b*CHN*TT;
  int o = rem / TT;
  float s = bias[o];
  #pragma unroll
  for (int cs = 0; cs < 8; ++cs) s += partial[(cs*2 + b)*CHN*TT + rem];
  h[idx] = fmaxf(s, 0.f);
}

// ---------------- fused q/k/v projection (multi-slot via blockIdx.z) ----------------
__global__ void qkv_kernel(const float* __restrict__ Wq_base, const float* __restrict__ Wk_base,
                           const float* __restrict__ Wv_base, int slot0,
                           const float* __restrict__ in,
                           float* __restrict__ q, float* __restrict__ k, float* __restrict__ v) {
  int t = blockIdx.x * 64 + threadIdx.x;
  int o = blockIdx.y;
  int z = blockIdx.z;
  int si = z >> 1, b = z & 1;
  if (t >= TT) return;
  const float* inb = in + b * CHN * TT;
  const float* wqr = Wq_base + (slot0+si)*CHN*CHN + o*CHN;
  const float* wkr = Wk_base + (slot0+si)*CHN*CHN + o*CHN;
  const float* wvr = Wv_base + (slot0+si)*CHN*CHN + o*CHN;
  float aq = 0.f, ak = 0.f, av = 0.f;
  #pragma unroll 8
  for (int c = 0; c < CHN; ++c) {
    float xv = inb[c*TT + t];
    aq += wqr[c] * xv;
    ak += wkr[c] * xv;
    av += wvr[c] * xv;
  }
  int off = si*CHN*TT*2 + (b*CHN + o)*TT + t;
  q[off] = aq;
  k[off] = ak;
  v[off] = av;
}

// ---------------- output projection: out = relu(W @ in) + resid (multi-slot) ----------------
__global__ void proj_kernel(const float* __restrict__ Wo_base, int slot0,
                            const float* __restrict__ in, const float* __restrict__ resid,
                            float* __restrict__ outb) {
  int t = blockIdx.x * 64 + threadIdx.x;
  int o = blockIdx.y;
  int z = blockIdx.z;
  int si = z >> 1, b = z & 1;
  if (t >= TT) return;
  const float* wrow = Wo_base + (slot0+si)*CHN*CHN + o*CHN;
  const float* inb = in + si*CHN*TT*2 + b*CHN*TT;
  float acc = 0.f;
  #pragma unroll 8
  for (int c = 0; c < CHN; ++c) acc += wrow[c] * inb[c*TT + t];
  acc = fmaxf(acc, 0.f) + resid[(b*CHN + o)*TT + t];
  outb[si*CHN*TT*2 + (b*CHN + o)*TT + t] = acc;
}

// ---------------- banded attention (multi-slot) ----------------
__global__ void attn_kernel(const float* __restrict__ q, const float* __restrict__ k,
                            const float* __restrict__ v, const float* __restrict__ pos,
                            float* __restrict__ Aout_base, long long Astride,
                            float* __restrict__ out) {
  int t = blockIdx.x;
  int z = blockIdx.y;
  int si = z >> 1, b = z & 1;
  int lane = threadIdx.x;  // 64
  const float* qb = q + si*CHN*TT*2 + b * CHN * TT;
  const float* kb = k + si*CHN*TT*2 + b * CHN * TT;
  const float* vb = v + si*CHN*TT*2 + b * CHN * TT;
  float qc[4];
  #pragma unroll
  for (int i = 0; i < 4; ++i) qc[i] = qb[(lane + 64*i)*TT + t];

  float sc[17];
  #pragma unroll
  for (int j = 0; j < 17; ++j) {
    int s = t - 8 + j;
    bool inr = (s >= 0) && (s < TT);
    int ss = s < 0 ? 0 : (s > TT-1 ? TT-1 : s);
    float p = 0.f;
    #pragma unroll
    for (int i = 0; i < 4; ++i) p += qc[i] * kb[(lane + 64*i)*TT + ss];
    #pragma unroll
    for (int off = 32; off > 0; off >>= 1) p += __shfl_xor(p, off, 64);
    sc[j] = inr ? (p * 0.0625f + pos[t*TT + ss]) : -3.0e38f;
  }
  float m8 = sc[0];
  #pragma unroll
  for (int j = 1; j < 17; ++j) m8 = fmaxf(m8, sc[j]);
  float m4 = sc[4];
  #pragma unroll
  for (int j = 5; j < 13; ++j) m4 = fmaxf(m4, sc[j]);
  float e8[17], s8 = 0.f;
  #pragma unroll
  for (int j = 0; j < 17; ++j) { e8[j] = expf(sc[j] - m8); s8 += e8[j]; }
  float e4[9], s4 = 0.f;
  #pragma unroll
  for (int j = 0; j < 9; ++j) { e4[j] = expf(sc[4+j] - m4); s4 += e4[j]; }
  float i8 = 1.f / s8, i4 = 1.f / s4;
  float asum[17];
  #pragma unroll
  for (int j = 0; j < 17; ++j) {
    float a = e8[j] * i8;
    if (j >= 4 && j <= 12) a += e4[j-4] * i4;
    asum[j] = a;
  }
  #pragma unroll
  for (int i = 0; i < 4; ++i) {
    float acc = 0.f;
    #pragma unroll
    for (int j = 0; j < 17; ++j) {
      int s = t - 8 + j;
      int ss = s < 0 ? 0 : (s > TT-1 ? TT-1 : s);
      acc += asum[j] * vb[(lane + 64*i)*TT + ss];
    }
    out[si*CHN*TT*2 + (b*CHN + lane + 64*i)*TT + t] = acc;
  }
  __shared__ float lds_a[17];
  #pragma unroll
  for (int j = 0; j < 17; ++j) if (lane == j) lds_a[j] = asum[j];
  __syncthreads();
  float* Aout = Aout_base + (long long)si * Astride;
  for (int s = lane; s < TT; s += 64) {
    int j = s - (t - 8);
    float a = (j >= 0 && j < 17) ? lds_a[j] : 0.f;
    Aout[(b*TT + t)*TT + s] = a;
  }
}

// ---------------- start/end head ----------------
__global__ void head_kernel(const float* __restrict__ feat, const float* __restrict__ w,
                            const float* __restrict__ bias, float* __restrict__ outp) {
  int t = blockIdx.x * 64 + threadIdx.x;
  int b = blockIdx.y;
  if (t >= TT) return;
  float acc = bias[0];
  #pragma unroll 8
  for (int c = 0; c < CHN; ++c) acc += w[c] * feat[(b*CHN + c)*TT + t];
  outp[b*TT + t] = 1.f / (1.f + expf(-acc));
}

// ---------------- transpose cw1 into wT[r][c][o] ----------------
__global__ void w1t_kernel(const float* __restrict__ cw1, float* __restrict__ wT) {
  int idx = blockIdx.x * 256 + threadIdx.x;
  if (idx >= 128 * 4096) return;
  int o = idx >> 12;
  int cr = idx & 4095;
  int c = cr >> 4;
  int r = cr & 15;
  wT[(r*CHN + c)*128 + o] = cw1[idx];
}

// ---------------- g[b][r][x][o] = sum_c wT[r][c][o] * cfeat[b][c][x] ----------------
__global__ void g_kernel(const float* __restrict__ wT, const float* __restrict__ cf,
                         float* __restrict__ g) {
  int o = threadIdx.x;      // 128
  int xt = blockIdx.x;      // 50 tiles of 4
  int r = blockIdx.y;       // 16
  int b = blockIdx.z;       // 2
  float acc[4] = {0.f, 0.f, 0.f, 0.f};
  const float* wp = wT + r*CHN*128 + o;
  const float* cp = cf + b*CHN*TT + xt*4;
  for (int c = 0; c < CHN; ++c) {
    float wv = wp[c*128];
    #pragma unroll
    for (int j = 0; j < 4; ++j) acc[j] += wv * cp[c*TT + j];
  }
  float* gp = g + ((b*RESN + r)*TT + xt*4)*128 + o;
  #pragma unroll
  for (int j = 0; j < 4; ++j) gp[j*128] = acc[j];
}

// ---------------- fused align + 1x1 conv (cw1) + relu -> y1[b][o][d][t] ----------------
__global__ void align_conv1_kernel(const float* __restrict__ g, const float* __restrict__ cb1,
                                   float* __restrict__ y1) {
  int o = threadIdx.x;      // 128
  int t = blockIdx.x;       // 200
  int d = blockIdx.y;       // 64
  int b = blockIdx.z;
  bool vanch = (t + d) < TT;
  float clen = d + 1.0f;
  float xmin = vanch ? (t - clen * 0.5f) : 0.f;
  float xmax = vanch ? (t + d + clen * 0.5f) : 0.f;
  float acc = cb1[o];
  const float* gb = g + b*RESN*TT*128;
  #pragma unroll
  for (int r = 0; r < RESN; ++r) {
    float frac = (r + 0.5f) * (1.f/16.f);
    float p = xmin + (xmax - xmin) * frac;
    float x0 = floorf(p);
    float wf = p - x0;
    int x0i = (int)fminf(fmaxf(x0, 0.f), (float)(TT-1));
    int x1i = (int)fminf(fmaxf(x0 + 1.f, 0.f), (float)(TT-1));
    bool vp = (p >= -1.0f) && (p <= (float)TT);
    if (vp) {
      const float* gr = gb + r*TT*128;
      acc += (1.f - wf) * gr[x0i*128 + o] + wf * gr[x1i*128 + o];
    }
  }
  y1[((b*128 + o)*DUR + d)*TT + t] = fmaxf(acc, 0.f);
}

// ---------------- LDS-tiled 3x3 conv 128->128, pad 1, relu ----------------
#define C3_CT 64
#define C3_CD 4
#define C3_COC 16
#define C3_CIC 8
__global__ __launch_bounds__(256, 4)
void conv3x3_kernel(const float* __restrict__ in, const float* __restrict__ w,
                    const float* __restrict__ bias, float* __restrict__ out) {
  __shared__ float tile[C3_CIC*6*68];
  __shared__ float wl[C3_COC*C3_CIC*12];
  int tid = threadIdx.x;
  int tl = tid & 63;
  int wg = tid >> 6;
  int t0 = blockIdx.x * C3_CT;
  int d0 = blockIdx.y * C3_CD;
  int z = blockIdx.z;
  int b = z >> 3;
  int ocg = z & 7;
  int t = t0 + tl;

  float acc[C3_CD][4];
  #pragma unroll
  for (int dd = 0; dd < C3_CD; ++dd)
    #pragma unroll
    for (int j = 0; j < 4; ++j) acc[dd][j] = 0.f;

  const float* inb = in + (size_t)b*128*DUR*TT;

  for (int ic0 = 0; ic0 < 128; ic0 += C3_CIC) {
    __syncthreads();
    for (int idx = tid; idx < C3_CIC*6*68; idx += 256) {
      int ic = idx / 408;
      int rem = idx - ic*408;
      int row = rem / 68;
      int col = rem - row*68;
      int gd = d0 + row - 1;
      int gt = t0 + col - 1;
      float vval = 0.f;
      if (col < 66 && (unsigned)gd < (unsigned)DUR && (unsigned)gt < (unsigned)TT)
        vval = inb[(ic0+ic)*DUR*TT + gd*TT + gt];
      tile[idx] = vval;
    }
    for (int idx = tid; idx < C3_COC*C3_CIC*12; idx += 256) {
      int oc = idx / (C3_CIC*12);
      int rem = idx - oc*C3_CIC*12;
      int ic = rem / 12;
      int kk = rem - ic*12;
      float vval = 0.f;
      if (kk < 9)
        vval = w[((ocg*C3_COC+oc)*128 + ic0+ic)*9 + kk];
      wl[idx] = vval;
    }
    __syncthreads();
    for (int ic = 0; ic < C3_CIC; ++ic) {
      float vv[6][3];
      #pragma unroll
      for (int r = 0; r < 6; ++r)
        #pragma unroll
        for (int c2 = 0; c2 < 3; ++c2)
          vv[r][c2] = tile[ic*408 + r*68 + tl + c2];
      #pragma unroll
      for (int j = 0; j < 4; ++j) {
        int oc_l = wg*4 + j;
        const float4* wp = (const float4*)(wl + (oc_l*C3_CIC + ic)*12);
        float4 w0 = wp[0], w1 = wp[1], w2 = wp[2];
        #pragma unroll
        for (int dd = 0; dd < C3_CD; ++dd) {
          float s = acc[dd][j];
          s += w0.x*vv[dd][0]   + w0.y*vv[dd][1]   + w0.z*vv[dd][2];
          s += w0.w*vv[dd+1][0] + w1.x*vv[dd+1][1] + w1.y*vv[dd+1][2];
          s += w1.z*vv[dd+2][0] + w1.w*vv[dd+2][1] + w2.x*vv[dd+2][2];
          acc[dd][j] = s;
        }
      }
    }
  }
  if (t < TT) {
    #pragma unroll
    for (int j = 0; j < 4; ++j) {
      int oc = ocg*C3_COC + wg*4 + j;
      float bv = bias[oc];
      #pragma unroll
      for (int dd = 0; dd < C3_CD; ++dd)
        out[((b*128+oc)*DUR + d0+dd)*TT + t] = fmaxf(acc[dd][j] + bv, 0.f);
    }
  }
}

// ---------------- final 1x1 conv 128->2 + sigmoid -> conf ----------------
__global__ void conv4_kernel(const float* __restrict__ in, const float* __restrict__ w,
                             const float* __restrict__ bias, float* __restrict__ conf) {
  int t = blockIdx.x * 64 + threadIdx.x;
  int d = blockIdx.y;
  int b = blockIdx.z;
  if (t >= TT) return;
  float a0 = bias[0], a1 = bias[1];
  #pragma unroll 4
  for (int i = 0; i < 128; ++i) {
    float vv = in[((b*128 + i)*DUR + d)*TT + t];
    a0 += w[i] * vv;
    a1 += w[128 + i] * vv;
  }
  conf[((b*2 + 0)*DUR + d)*TT + t] = 1.f / (1.f + expf(-a0));
  conf[((b*2 + 1)*DUR + d)*TT + t] = 1.f / (1.f + expf(-a1));
}

extern "C" void kernel_launch(void* const* d_in, const int* in_sizes, int n_in,
                              void* d_out, int out_size, void* d_ws, size_t ws_size,
                              hipStream_t stream) {
  const float* x       = (const float*)d_in[0];
  const float* base_w  = (const float*)d_in[1];
  const float* base_b  = (const float*)d_in[2];
  const float* wq      = (const float*)d_in[3];
  const float* wk      = (const float*)d_in[4];
  const float* wv      = (const float*)d_in[5];
  const float* wo      = (const float*)d_in[6];
  const float* pos     = (const float*)d_in[7];
  const float* start_w = (const float*)d_in[8];
  const float* start_b = (const float*)d_in[9];
  const float* end_w   = (const float*)d_in[10];
  const float* end_b   = (const float*)d_in[11];
  const float* cw1     = (const float*)d_in[12];
  const float* cb1     = (const float*)d_in[13];
  const float* cw2     = (const float*)d_in[14];
  const float* cb2     = (const float*)d_in[15];
  const float* cw3     = (const float*)d_in[16];
  const float* cb3     = (const float*)d_in[17];
  const float* cw4     = (const float*)d_in[18];
  const float* cb4     = (const float*)d_in[19];

  float* out = (float*)d_out;
  float* conf_out  = out;            // 51200
  float* start_out = out + 51200;    // 400
  float* end_out   = out + 51600;    // 400
  float* As_out    = out + 52000;    // 80000 (Ae, Ap follow at stride 80000)

  // workspace layout (floats), with overlays (sequential-stream safe)
  float* ws = (float*)d_ws;
  float* h      = ws;                 // 102400
  float* basef  = ws + 102400;        // 102400
  float* feats3 = ws + 204800;        // 307200: sfeat, efeat, cfeat
  float* wT     = ws + 512000;        // 524288
  float* gbuf   = ws + 1036288;       // 819200
  float* y1     = ws + 1855488;       // 3276800
  float* y2     = ws + 5132288;       // 3276800
  // overlays inside y1 (all dead before align writes y1):
  float* qb3    = y1;                 // 307200
  float* kb3    = y1 + 307200;        // 307200
  float* vb3    = y1 + 614400;        // 307200
  float* ao3    = y1 + 921600;        // 307200
  float* partial= y1 + 1228800;       // 819200
  // overlay inside y2 (dead before conv3x3 writes y2):
  float* A_scr  = y2;                 // 80000

  dim3 b64(64);
  dim3 b256(256);

  // base conv: partial over 8 c-slices, then reduce
  base_conv_part<<<dim3(4, 16, 16), b256, 0, stream>>>(x, base_w, partial);
  base_reduce<<<dim3(400), b256, 0, stream>>>(partial, base_b, h);

  // rslot 0 (h -> basef)
  qkv_kernel<<<dim3(4, 256, 2), b64, 0, stream>>>(wq, wk, wv, 0, h, qb3, kb3, vb3);
  attn_kernel<<<dim3(200, 2), b64, 0, stream>>>(qb3, kb3, vb3, pos, A_scr, 0, ao3);
  proj_kernel<<<dim3(4, 256, 2), b64, 0, stream>>>(wo, 0, ao3, h, basef);

  // rslots 1-3 batched (basef -> feats3[si]), A -> d_out directly
  qkv_kernel<<<dim3(4, 256, 6), b64, 0, stream>>>(wq, wk, wv, 1, basef, qb3, kb3, vb3);
  attn_kernel<<<dim3(200, 6), b64, 0, stream>>>(qb3, kb3, vb3, pos, As_out, 80000, ao3);
  proj_kernel<<<dim3(4, 256, 6), b64, 0, stream>>>(wo, 1, ao3, basef, feats3);

  // heads
  head_kernel<<<dim3(4, 2), b64, 0, stream>>>(feats3, start_w, start_b, start_out);
  head_kernel<<<dim3(4, 2), b64, 0, stream>>>(feats3 + 102400, end_w, end_b, end_out);

  // proposal branch
  const float* cfeat = feats3 + 204800;
  w1t_kernel<<<dim3(2048), b256, 0, stream>>>(cw1, wT);
  g_kernel<<<dim3(50, 16, 2), dim3(128), 0, stream>>>(wT, cfeat, gbuf);
  align_conv1_kernel<<<dim3(200, 64, 2), dim3(128), 0, stream>>>(gbuf, cb1, y1);
  conv3x3_kernel<<<dim3(4, 16, 16), b256, 0, stream>>>(y1, cw2, cb2, y2);
  conv3x3_kernel<<<dim3(4, 16, 16), b256, 0, stream>>>(y2, cw3, cb3, y1);
  conv4_kernel<<<dim3(4, 64, 2), b64, 0, stream>>>(y1, cw4, cb4, conf_out);
}

// Round 4
// 813.525 us; speedup vs baseline: 1.6280x; 1.0801x over previous
//
#include <hip/hip_runtime.h>
#include <math.h>

#define TT 200
#define CHN 256
#define FEAT 2048
#define DUR 64
#define RESN 16

// ---------------- base conv1d partial: 16oc x 64t tile over 256-c slice ----------------
__global__ __launch_bounds__(256, 4)
void base_conv_part(const float* __restrict__ x, const float* __restrict__ w,
                    float* __restrict__ partial) {
  __shared__ float xt[16*68];
  __shared__ float wl[16*16*4];
  int tid = threadIdx.x;
  int tl = tid & 63, wg = tid >> 6;
  int t0 = blockIdx.x * 64;
  int ocg = blockIdx.y;
  int cs = blockIdx.z >> 1, b = blockIdx.z & 1;
  const float* xb = x + (size_t)b * FEAT * TT;
  float acc[4] = {0.f, 0.f, 0.f, 0.f};

  for (int ch = 0; ch < 16; ++ch) {
    int c0 = cs * 256 + ch * 16;
    __syncthreads();
    for (int idx = tid; idx < 16*68; idx += 256) {
      int ic = idx / 68, col = idx - ic*68;
      int gt = t0 + col - 1;
      float v = 0.f;
      if (col < 66 && (unsigned)gt < (unsigned)TT) v = xb[(c0+ic)*TT + gt];
      xt[idx] = v;
    }
    for (int idx = tid; idx < 16*16*3; idx += 256) {
      int oc = idx / 48, rem = idx - oc*48;
      int ic = rem / 3, kk = rem - ic*3;
      wl[(oc*16 + ic)*4 + kk] = w[((ocg*16+oc)*FEAT + c0+ic)*3 + kk];
    }
    __syncthreads();
    #pragma unroll
    for (int ic = 0; ic < 16; ++ic) {
      float v0 = xt[ic*68 + tl];
      float v1 = xt[ic*68 + tl + 1];
      float v2 = xt[ic*68 + tl + 2];
      #pragma unroll
      for (int j = 0; j < 4; ++j) {
        const float4 wv = *(const float4*)(wl + ((wg*4+j)*16 + ic)*4);
        acc[j] += wv.x*v0 + wv.y*v1 + wv.z*v2;
      }
    }
  }
  int t = t0 + tl;
  if (t < TT) {
    #pragma unroll
    for (int j = 0; j < 4; ++j) {
      int oc = ocg*16 + wg*4 + j;
      partial[((cs*2 + b)*CHN + oc)*TT + t] = acc[j];
    }
  }
}

__global__ void base_reduce(const float* __restrict__ partial, const float* __restrict__ bias,
                            float* __restrict__ h) {
  int idx = blockIdx.x * 256 + threadIdx.x;
  if (idx >= 2*CHN*TT) return;
  int b = idx / (CHN*TT);
  int rem = idx - b*CHN*TT;
  int o = rem / TT;
  float s = bias[o];
  #pragma unroll
  for (int cs = 0; cs < 8; ++cs) s += partial[(cs*2 + b)*CHN*TT + rem];
  h[idx] = fmaxf(s, 0.f);
}

// ---------------- fused q/k/v projection (multi-slot via blockIdx.z) ----------------
__global__ void qkv_kernel(const float* __restrict__ Wq_base, const float* __restrict__ Wk_base,
                           const float* __restrict__ Wv_base, int slot0,
                           const float* __restrict__ in,
                           float* __restrict__ q, float* __restrict__ k, float* __restrict__ v) {
  int t = blockIdx.x * 64 + threadIdx.x;
  int o = blockIdx.y;
  int z = blockIdx.z;
  int si = z >> 1, b = z & 1;
  if (t >= TT) return;
  const float* inb = in + b * CHN * TT;
  const float* wqr = Wq_base + (slot0+si)*CHN*CHN + o*CHN;
  const float* wkr = Wk_base + (slot0+si)*CHN*CHN + o*CHN;
  const float* wvr = Wv_base + (slot0+si)*CHN*CHN + o*CHN;
  float aq0 = 0.f, ak0 = 0.f, av0 = 0.f;
  float aq1 = 0.f, ak1 = 0.f, av1 = 0.f;
  #pragma unroll 4
  for (int c = 0; c < 128; ++c) {
    float x0 = inb[c*TT + t];
    float x1 = inb[(c+128)*TT + t];
    aq0 += wqr[c] * x0;      aq1 += wqr[c+128] * x1;
    ak0 += wkr[c] * x0;      ak1 += wkr[c+128] * x1;
    av0 += wvr[c] * x0;      av1 += wvr[c+128] * x1;
  }
  int off = si*CHN*TT*2 + (b*CHN + o)*TT + t;
  q[off] = aq0 + aq1;
  k[off] = ak0 + ak1;
  v[off] = av0 + av1;
}

// ---------------- output projection: out = relu(W @ in) + resid (multi-slot) ----------------
__global__ void proj_kernel(const float* __restrict__ Wo_base, int slot0,
                            const float* __restrict__ in, const float* __restrict__ resid,
                            float* __restrict__ outb) {
  int t = blockIdx.x * 64 + threadIdx.x;
  int o = blockIdx.y;
  int z = blockIdx.z;
  int si = z >> 1, b = z & 1;
  if (t >= TT) return;
  const float* wrow = Wo_base + (slot0+si)*CHN*CHN + o*CHN;
  const float* inb = in + si*CHN*TT*2 + b*CHN*TT;
  float a0 = 0.f, a1 = 0.f, a2 = 0.f, a3 = 0.f;
  #pragma unroll 4
  for (int c = 0; c < 64; ++c) {
    a0 += wrow[c]     * inb[c*TT + t];
    a1 += wrow[c+64]  * inb[(c+64)*TT + t];
    a2 += wrow[c+128] * inb[(c+128)*TT + t];
    a3 += wrow[c+192] * inb[(c+192)*TT + t];
  }
  float acc = (a0 + a1) + (a2 + a3);
  acc = fmaxf(acc, 0.f) + resid[(b*CHN + o)*TT + t];
  outb[si*CHN*TT*2 + (b*CHN + o)*TT + t] = acc;
}

// ---------------- banded attention (multi-slot) ----------------
__global__ void attn_kernel(const float* __restrict__ q, const float* __restrict__ k,
                            const float* __restrict__ v, const float* __restrict__ pos,
                            float* __restrict__ Aout_base, long long Astride,
                            float* __restrict__ out) {
  int t = blockIdx.x;
  int z = blockIdx.y;
  int si = z >> 1, b = z & 1;
  int lane = threadIdx.x;  // 64
  const float* qb = q + si*CHN*TT*2 + b * CHN * TT;
  const float* kb = k + si*CHN*TT*2 + b * CHN * TT;
  const float* vb = v + si*CHN*TT*2 + b * CHN * TT;
  float qc[4];
  #pragma unroll
  for (int i = 0; i < 4; ++i) qc[i] = qb[(lane + 64*i)*TT + t];

  float sc[17];
  #pragma unroll
  for (int j = 0; j < 17; ++j) {
    int s = t - 8 + j;
    bool inr = (s >= 0) && (s < TT);
    int ss = s < 0 ? 0 : (s > TT-1 ? TT-1 : s);
    float p = 0.f;
    #pragma unroll
    for (int i = 0; i < 4; ++i) p += qc[i] * kb[(lane + 64*i)*TT + ss];
    #pragma unroll
    for (int off = 32; off > 0; off >>= 1) p += __shfl_xor(p, off, 64);
    sc[j] = inr ? (p * 0.0625f + pos[t*TT + ss]) : -3.0e38f;
  }
  float m8 = sc[0];
  #pragma unroll
  for (int j = 1; j < 17; ++j) m8 = fmaxf(m8, sc[j]);
  float m4 = sc[4];
  #pragma unroll
  for (int j = 5; j < 13; ++j) m4 = fmaxf(m4, sc[j]);
  float e8[17], s8 = 0.f;
  #pragma unroll
  for (int j = 0; j < 17; ++j) { e8[j] = expf(sc[j] - m8); s8 += e8[j]; }
  float e4[9], s4 = 0.f;
  #pragma unroll
  for (int j = 0; j < 9; ++j) { e4[j] = expf(sc[4+j] - m4); s4 += e4[j]; }
  float i8 = 1.f / s8, i4 = 1.f / s4;
  float asum[17];
  #pragma unroll
  for (int j = 0; j < 17; ++j) {
    float a = e8[j] * i8;
    if (j >= 4 && j <= 12) a += e4[j-4] * i4;
    asum[j] = a;
  }
  #pragma unroll
  for (int i = 0; i < 4; ++i) {
    float acc = 0.f;
    #pragma unroll
    for (int j = 0; j < 17; ++j) {
      int s = t - 8 + j;
      int ss = s < 0 ? 0 : (s > TT-1 ? TT-1 : s);
      acc += asum[j] * vb[(lane + 64*i)*TT + ss];
    }
    out[si*CHN*TT*2 + (b*CHN + lane + 64*i)*TT + t] = acc;
  }
  __shared__ float lds_a[17];
  #pragma unroll
  for (int j = 0; j < 17; ++j) if (lane == j) lds_a[j] = asum[j];
  __syncthreads();
  float* Aout = Aout_base + (long long)si * Astride;
  for (int s = lane; s < TT; s += 64) {
    int j = s - (t - 8);
    float a = (j >= 0 && j < 17) ? lds_a[j] : 0.f;
    Aout[(b*TT + t)*TT + s] = a;
  }
}

// ---------------- start/end head ----------------
__global__ void head_kernel(const float* __restrict__ feat, const float* __restrict__ w,
                            const float* __restrict__ bias, float* __restrict__ outp) {
  int t = blockIdx.x * 64 + threadIdx.x;
  int b = blockIdx.y;
  if (t >= TT) return;
  float acc = bias[0];
  #pragma unroll 8
  for (int c = 0; c < CHN; ++c) acc += w[c] * feat[(b*CHN + c)*TT + t];
  outp[b*TT + t] = 1.f / (1.f + expf(-acc));
}

// ---------------- transpose cw1 into wT[r][c][o] ----------------
__global__ void w1t_kernel(const float* __restrict__ cw1, float* __restrict__ wT) {
  int idx = blockIdx.x * 256 + threadIdx.x;
  if (idx >= 128 * 4096) return;
  int o = idx >> 12;
  int cr = idx & 4095;
  int c = cr >> 4;
  int r = cr & 15;
  wT[(r*CHN + c)*128 + o] = cw1[idx];
}

// ---------------- g[b][r][x][o] = sum_c wT[r][c][o] * cfeat[b][c][x] ----------------
__global__ void g_kernel(const float* __restrict__ wT, const float* __restrict__ cf,
                         float* __restrict__ g) {
  int o = threadIdx.x;      // 128
  int xt = blockIdx.x;      // 50 tiles of 4
  int r = blockIdx.y;       // 16
  int b = blockIdx.z;       // 2
  float acc[4] = {0.f, 0.f, 0.f, 0.f};
  const float* wp = wT + r*CHN*128 + o;
  const float* cp = cf + b*CHN*TT + xt*4;
  for (int c = 0; c < CHN; ++c) {
    float wv = wp[c*128];
    #pragma unroll
    for (int j = 0; j < 4; ++j) acc[j] += wv * cp[c*TT + j];
  }
  float* gp = g + ((b*RESN + r)*TT + xt*4)*128 + o;
  #pragma unroll
  for (int j = 0; j < 4; ++j) gp[j*128] = acc[j];
}

// ---------------- fused align + 1x1 conv (cw1) + relu -> y1[b][o][d][t] ----------------
__global__ void align_conv1_kernel(const float* __restrict__ g, const float* __restrict__ cb1,
                                   float* __restrict__ y1) {
  int o = threadIdx.x;      // 128
  int t = blockIdx.x;       // 200
  int d = blockIdx.y;       // 64
  int b = blockIdx.z;
  bool vanch = (t + d) < TT;
  float clen = d + 1.0f;
  float xmin = vanch ? (t - clen * 0.5f) : 0.f;
  float xmax = vanch ? (t + d + clen * 0.5f) : 0.f;
  float acc = cb1[o];
  const float* gb = g + b*RESN*TT*128;
  #pragma unroll
  for (int r = 0; r < RESN; ++r) {
    float frac = (r + 0.5f) * (1.f/16.f);
    float p = xmin + (xmax - xmin) * frac;
    float x0 = floorf(p);
    float wf = p - x0;
    int x0i = (int)fminf(fmaxf(x0, 0.f), (float)(TT-1));
    int x1i = (int)fminf(fmaxf(x0 + 1.f, 0.f), (float)(TT-1));
    bool vp = (p >= -1.0f) && (p <= (float)TT);
    if (vp) {
      const float* gr = gb + r*TT*128;
      acc += (1.f - wf) * gr[x0i*128 + o] + wf * gr[x1i*128 + o];
    }
  }
  y1[((b*128 + o)*DUR + d)*TT + t] = fmaxf(acc, 0.f);
}

// ---------------- 3x3 conv v2: scalar weights, double-buffered input tile ----------------
// Block 256 = 4 waves; output tile 16 oc x 4 d x 64 t; grid (4, 16, b*8+ocg) = 1024.
// LDS: 2 x [6 rows x 8 ic x 68 cols]; weights via s_load (wave-uniform addresses).
__global__ __launch_bounds__(256, 4)
void conv3x3_kernel(const float* __restrict__ in, const float* __restrict__ w,
                    const float* __restrict__ bias, float* __restrict__ out) {
  __shared__ float tile[2][6*8*68];
  int tid = threadIdx.x;
  int tl = tid & 63;
  int wg = tid >> 6;
  int t0 = blockIdx.x * 64;
  int d0 = blockIdx.y * 4;
  int z = blockIdx.z;
  int b = z >> 3;
  int ocg = z & 7;
  const float* inb = in + (size_t)b*128*DUR*TT;
  int wgu = __builtin_amdgcn_readfirstlane(wg);
  const float* wb = w + (size_t)(ocg*16 + wgu*4)*128*9;

  float acc[4][4];
  #pragma unroll
  for (int dd = 0; dd < 4; ++dd)
    #pragma unroll
    for (int j = 0; j < 4; ++j) acc[dd][j] = 0.f;

  int gt = t0 + tl - 1;
  bool tok0 = (unsigned)gt < (unsigned)TT;
  bool tok1 = (tl < 4) && ((unsigned)(gt+64) < (unsigned)TT);

  // stage (row,ic) pairs: pass p handles pair p*4+wg; layout tile[pair*68 + col]
  #define C3_STAGE(BUF, IC0)                                                     \
    {                                                                            \
      _Pragma("unroll")                                                          \
      for (int p = 0; p < 12; ++p) {                                             \
        int pair = p*4 + wg;                                                     \
        int row = pair >> 3, ic = pair & 7;                                      \
        int gd = d0 + row - 1;                                                   \
        bool dok = (unsigned)gd < (unsigned)DUR;                                 \
        const float* src = inb + ((IC0)+ic)*DUR*TT + gd*TT + gt;                 \
        float v0 = (dok && tok0) ? src[0] : 0.f;                                 \
        tile[BUF][pair*68 + tl] = v0;                                            \
        if (tl < 4) {                                                            \
          float v1 = (dok && tok1) ? src[64] : 0.f;                              \
          tile[BUF][pair*68 + tl + 64] = v1;                                     \
        }                                                                        \
      }                                                                          \
    }

  C3_STAGE(0, 0)
  __syncthreads();
  int buf = 0;
  for (int blk = 0; blk < 16; ++blk) {
    if (blk < 15) {
      if (buf == 0) C3_STAGE(1, (blk+1)*8)
      else          C3_STAGE(0, (blk+1)*8)
    }
    const float* wblk = wb + (size_t)blk*8*9;
    #pragma unroll 2
    for (int ic = 0; ic < 8; ++ic) {
      float vv[6][3];
      #pragma unroll
      for (int r = 0; r < 6; ++r)
        #pragma unroll
        for (int c2 = 0; c2 < 3; ++c2)
          vv[r][c2] = tile[buf][(r*8+ic)*68 + tl + c2];
      #pragma unroll
      for (int j = 0; j < 4; ++j) {
        const float* wj = wblk + (size_t)j*128*9 + ic*9;
        float w0=wj[0], w1=wj[1], w2=wj[2], w3=wj[3], w4=wj[4],
              w5=wj[5], w6=wj[6], w7=wj[7], w8=wj[8];
        #pragma unroll
        for (int dd = 0; dd < 4; ++dd) {
          float s = acc[dd][j];
          s += w0*vv[dd][0]   + w1*vv[dd][1]   + w2*vv[dd][2];
          s += w3*vv[dd+1][0] + w4*vv[dd+1][1] + w5*vv[dd+1][2];
          s += w6*vv[dd+2][0] + w7*vv[dd+2][1] + w8*vv[dd+2][2];
          acc[dd][j] = s;
        }
      }
    }
    __syncthreads();
    buf ^= 1;
  }
  #undef C3_STAGE

  int t = t0 + tl;
  if (t < TT) {
    #pragma unroll
    for (int j = 0; j < 4; ++j) {
      int oc = ocg*16 + wgu*4 + j;
      float bv = bias[oc];
      #pragma unroll
      for (int dd = 0; dd < 4; ++dd)
        out[((b*128+oc)*DUR + d0+dd)*TT + t] = fmaxf(acc[dd][j] + bv, 0.f);
    }
  }
}

// ---------------- final 1x1 conv 128->2 + sigmoid -> conf ----------------
__global__ void conv4_kernel(const float* __restrict__ in, const float* __restrict__ w,
                             const float* __restrict__ bias, float* __restrict__ conf) {
  int t = blockIdx.x * 64 + threadIdx.x;
  int d = blockIdx.y;
  int b = blockIdx.z;
  if (t >= TT) return;
  float a0 = bias[0], a1 = bias[1];
  #pragma unroll 4
  for (int i = 0; i < 128; ++i) {
    float vv = in[((b*128 + i)*DUR + d)*TT + t];
    a0 += w[i] * vv;
    a1 += w[128 + i] * vv;
  }
  conf[((b*2 + 0)*DUR + d)*TT + t] = 1.f / (1.f + expf(-a0));
  conf[((b*2 + 1)*DUR + d)*TT + t] = 1.f / (1.f + expf(-a1));
}

extern "C" void kernel_launch(void* const* d_in, const int* in_sizes, int n_in,
                              void* d_out, int out_size, void* d_ws, size_t ws_size,
                              hipStream_t stream) {
  const float* x       = (const float*)d_in[0];
  const float* base_w  = (const float*)d_in[1];
  const float* base_b  = (const float*)d_in[2];
  const float* wq      = (const float*)d_in[3];
  const float* wk      = (const float*)d_in[4];
  const float* wv      = (const float*)d_in[5];
  const float* wo      = (const float*)d_in[6];
  const float* pos     = (const float*)d_in[7];
  const float* start_w = (const float*)d_in[8];
  const float* start_b = (const float*)d_in[9];
  const float* end_w   = (const float*)d_in[10];
  const float* end_b   = (const float*)d_in[11];
  const float* cw1     = (const float*)d_in[12];
  const float* cb1     = (const float*)d_in[13];
  const float* cw2     = (const float*)d_in[14];
  const float* cb2     = (const float*)d_in[15];
  const float* cw3     = (const float*)d_in[16];
  const float* cb3     = (const float*)d_in[17];
  const float* cw4     = (const float*)d_in[18];
  const float* cb4     = (const float*)d_in[19];

  float* out = (float*)d_out;
  float* conf_out  = out;
  float* start_out = out + 51200;
  float* end_out   = out + 51600;
  float* As_out    = out + 52000;    // Ae, Ap follow at stride 80000

  float* ws = (float*)d_ws;
  float* h      = ws;                 // 102400
  float* basef  = ws + 102400;        // 102400
  float* feats3 = ws + 204800;        // 307200
  float* wT     = ws + 512000;        // 524288
  float* gbuf   = ws + 1036288;       // 819200
  float* y1     = ws + 1855488;       // 3276800
  float* y2     = ws + 5132288;       // 3276800
  float* qb3    = y1;                 // overlays in y1
  float* kb3    = y1 + 307200;
  float* vb3    = y1 + 614400;
  float* ao3    = y1 + 921600;
  float* partial= y1 + 1228800;
  float* A_scr  = y2;                 // overlay in y2

  dim3 b64(64);
  dim3 b256(256);

  base_conv_part<<<dim3(4, 16, 16), b256, 0, stream>>>(x, base_w, partial);
  base_reduce<<<dim3(400), b256, 0, stream>>>(partial, base_b, h);

  qkv_kernel<<<dim3(4, 256, 2), b64, 0, stream>>>(wq, wk, wv, 0, h, qb3, kb3, vb3);
  attn_kernel<<<dim3(200, 2), b64, 0, stream>>>(qb3, kb3, vb3, pos, A_scr, 0, ao3);
  proj_kernel<<<dim3(4, 256, 2), b64, 0, stream>>>(wo, 0, ao3, h, basef);

  qkv_kernel<<<dim3(4, 256, 6), b64, 0, stream>>>(wq, wk, wv, 1, basef, qb3, kb3, vb3);
  attn_kernel<<<dim3(200, 6), b64, 0, stream>>>(qb3, kb3, vb3, pos, As_out, 80000, ao3);
  proj_kernel<<<dim3(4, 256, 6), b64, 0, stream>>>(wo, 1, ao3, basef, feats3);

  head_kernel<<<dim3(4, 2), b64, 0, stream>>>(feats3, start_w, start_b, start_out);
  head_kernel<<<dim3(4, 2), b64, 0, stream>>>(feats3 + 102400, end_w, end_b, end_out);

  const float* cfeat = feats3 + 204800;
  w1t_kernel<<<dim3(2048), b256, 0, stream>>>(cw1, wT);
  g_kernel<<<dim3(50, 16, 2), dim3(128), 0, stream>>>(wT, cfeat, gbuf);
  align_conv1_kernel<<<dim3(200, 64, 2), dim3(128), 0, stream>>>(gbuf, cb1, y1);
  conv3x3_kernel<<<dim3(4, 16, 16), b256, 0, stream>>>(y1, cw2, cb2, y2);
  conv3x3_kernel<<<dim3(4, 16, 16), b256, 0, stream>>>(y2, cw3, cb3, y1);
  conv4_kernel<<<dim3(4, 64, 2), b64, 0, stream>>>(y1, cw4, cb4, conf_out);
}